// Round 3
// baseline (115.803 us; speedup 1.0000x reference)
//
#include <hip/hip_runtime.h>

// Chamfer distance via MFMA, B=4, N=M=8192, D=3, fp32.
// w(i,j) = q_i.t_j - 0.5|q_i|^2 - 0.5|t_j|^2 = -d^2/2  (symmetric in roles)
//   -> one 32x32x16 bf16 MFMA yields a 32x32 tile of w (1024 pairs);
//      row-max(w) = c1->c2 NN, col-max(w) = c2->c1 NN from the SAME tile.
// Precision: coords + half-norms split into bf16 hi+lo; per-point 16-slot
// K-vector so the MFMA computes w directly (err ~1e-5 on d^2, threshold 30.6):
//   A(point q) = [qh(3), ql(3), qh(3), hq_h, hq_l,  1,  1, 0,0,0]
//   B(point t) = [th(3), th(3), tl(3),  -1,  -1, -ht_h, -ht_l, 0,0,0]
// Pipeline: prep (pack reps) -> init (minbufs) -> chamfer_mfma (tiles, atomic
// max of order-encoded w) -> loss (d = -2w, reduce) -> final.

#define NPTS   8192
#define BATCH  4
#define NJ     4
#define JCHUNK (NPTS / NJ)     // 2048 targets per block
#define JTILES (JCHUNK / 32)   // 64 MFMA tiles per wave
#define NSLOTS (2 * BATCH * NPTS)  // 65536

typedef __attribute__((ext_vector_type(8))) short short8v;   // 8 bf16
typedef __attribute__((ext_vector_type(16))) float f32x16;

__device__ __forceinline__ unsigned enc_f32(float f) {
  unsigned u = __float_as_uint(f);
  return (u & 0x80000000u) ? ~u : (u | 0x80000000u);
}
__device__ __forceinline__ float dec_f32(unsigned u) {
  u = (u & 0x80000000u) ? (u ^ 0x80000000u) : ~u;
  return __uint_as_float(u);
}
__device__ __forceinline__ unsigned short f2bf(float x) {   // RNE bf16
  unsigned u = __float_as_uint(x);
  unsigned r = u + 0x7FFFu + ((u >> 16) & 1u);
  return (unsigned short)(r >> 16);
}
__device__ __forceinline__ float bf2f(unsigned short b) {
  return __uint_as_float((unsigned)b << 16);
}

__global__ __launch_bounds__(256) void init_min(unsigned* __restrict__ minbuf) {
  int i = blockIdx.x * 256 + threadIdx.x;
  if (i < NSLOTS) minbuf[i] = 0u;   // below enc of any real float
}

__global__ __launch_bounds__(256) void prep(
    const float* __restrict__ c1, const float* __restrict__ c2,
    unsigned short* __restrict__ arep, unsigned short* __restrict__ brep) {
  int pid = blockIdx.x * 256 + threadIdx.x;   // 0..32767 = (b, point)
  if (pid >= BATCH * NPTS) return;
  const unsigned short one = 0x3F80u, negone = 0xBF80u;
  {  // cloud1 -> A-side rep
    float x = c1[pid * 3 + 0], y = c1[pid * 3 + 1], z = c1[pid * 3 + 2];
    unsigned short xh = f2bf(x), yh = f2bf(y), zh = f2bf(z);
    unsigned short xl = f2bf(x - bf2f(xh)), yl = f2bf(y - bf2f(yh)), zl = f2bf(z - bf2f(zh));
    float hq = 0.5f * (x * x + y * y + z * z);
    unsigned short hh = f2bf(hq), hl = f2bf(hq - bf2f(hh));
    unsigned short v[16] = {xh, yh, zh, xl, yl, zl, xh, yh, zh, hh, hl, one, one, 0, 0, 0};
    uint4* dst = (uint4*)(arep + (size_t)pid * 16);
    dst[0] = *(const uint4*)&v[0];
    dst[1] = *(const uint4*)&v[8];
  }
  {  // cloud2 -> B-side rep
    float x = c2[pid * 3 + 0], y = c2[pid * 3 + 1], z = c2[pid * 3 + 2];
    unsigned short xh = f2bf(x), yh = f2bf(y), zh = f2bf(z);
    unsigned short xl = f2bf(x - bf2f(xh)), yl = f2bf(y - bf2f(yh)), zl = f2bf(z - bf2f(zh));
    float ht = 0.5f * (x * x + y * y + z * z);
    unsigned short hh = f2bf(ht), hl = f2bf(ht - bf2f(hh));
    unsigned short nh = hh ^ 0x8000u, nl = hl ^ 0x8000u;  // -ht_hi, -ht_lo
    unsigned short v[16] = {xh, yh, zh, xh, yh, zh, xl, yl, zl, negone, negone, nh, nl, 0, 0, 0};
    uint4* dst = (uint4*)(brep + (size_t)pid * 16);
    dst[0] = *(const uint4*)&v[0];
    dst[1] = *(const uint4*)&v[8];
  }
}

// grid = 4(b) x 64(iblk) x NJ(jchunk) = 1024 blocks of 4 waves.
// Wave w handles i-tile = iblk*4+w (32 queries), loops JTILES target tiles.
__global__ __launch_bounds__(256, 4) void chamfer_mfma(
    const unsigned short* __restrict__ arep, const unsigned short* __restrict__ brep,
    unsigned* __restrict__ rowbuf, unsigned* __restrict__ colbuf) {
  int bid  = blockIdx.x;
  int jc   = bid & (NJ - 1);
  int iblk = (bid >> 2) & 63;
  int b    = bid >> 8;
  int wave = threadIdx.x >> 6;
  int lane = threadIdx.x & 63;
  int i0 = (iblk * 4 + wave) * 32;
  int j0 = jc * JCHUNK;

  // A fragment: lane holds point i0+(lane&31), k-half (lane>>5), 8 bf16.
  const unsigned short* Ap =
      arep + ((size_t)b * NPTS + i0 + (lane & 31)) * 16 + (lane >> 5) * 8;
  short8v afrag = *(const short8v*)(const void*)Ap;

  const unsigned short* Bp =
      brep + ((size_t)b * NPTS + j0 + (lane & 31)) * 16 + (lane >> 5) * 8;

  f32x16 zero;
  #pragma unroll
  for (int i = 0; i < 16; ++i) zero[i] = 0.0f;

  f32x16 mrow;
  #pragma unroll
  for (int i = 0; i < 16; ++i) mrow[i] = -3.4e38f;

  unsigned* colb = colbuf + (size_t)b * NPTS + j0;

  #pragma unroll 4
  for (int jt = 0; jt < JTILES; ++jt) {
    short8v bfrag = *(const short8v*)(const void*)(Bp + (size_t)jt * 32 * 16);
    f32x16 acc = __builtin_amdgcn_mfma_f32_32x32x16_bf16(afrag, bfrag, zero, 0, 0, 0);
    // row running max (col-slice per lane)
    #pragma unroll
    for (int r = 0; r < 16; ++r) mrow[r] = fmaxf(mrow[r], acc[r]);
    // col max: tree over this lane's 16 rows, then combine lane halves
    float t = fmaxf(
        fmaxf(fmaxf(fmaxf(acc[0], acc[1]), fmaxf(acc[2], acc[3])),
              fmaxf(fmaxf(acc[4], acc[5]), fmaxf(acc[6], acc[7]))),
        fmaxf(fmaxf(fmaxf(acc[8], acc[9]), fmaxf(acc[10], acc[11])),
              fmaxf(fmaxf(acc[12], acc[13]), fmaxf(acc[14], acc[15]))));
    t = fmaxf(t, __shfl_xor(t, 32, 64));
    if (lane < 32) atomicMax(colb + jt * 32 + lane, enc_f32(t));
  }

  // row-max: butterfly across the 32 lanes of each half (cols), then atomics
  #pragma unroll
  for (int r = 0; r < 16; ++r) {
    float v = mrow[r];
    v = fmaxf(v, __shfl_xor(v, 1, 64));
    v = fmaxf(v, __shfl_xor(v, 2, 64));
    v = fmaxf(v, __shfl_xor(v, 4, 64));
    v = fmaxf(v, __shfl_xor(v, 8, 64));
    v = fmaxf(v, __shfl_xor(v, 16, 64));
    mrow[r] = v;
  }
  if ((lane & 31) == 0) {
    int half = lane >> 5;
    unsigned* rowb = rowbuf + (size_t)b * NPTS + i0;
    #pragma unroll
    for (int r = 0; r < 16; ++r) {
      int row = (r & 3) + 8 * (r >> 2) + 4 * half;   // verified 32x32 C/D map
      atomicMax(rowb + row, enc_f32(mrow[r]));
    }
  }
}

__global__ __launch_bounds__(256) void chamfer_loss(
    const unsigned* __restrict__ minbuf, float* __restrict__ partials) {
  int slot = blockIdx.x * 256 + threadIdx.x;
  float w = dec_f32(minbuf[slot]);
  float d2 = -2.0f * w;   // = min squared distance for this point
  float s = d2;
  #pragma unroll
  for (int off = 32; off > 0; off >>= 1) s += __shfl_down(s, off, 64);
  __shared__ float wsum[4];
  if ((threadIdx.x & 63) == 0) wsum[threadIdx.x >> 6] = s;
  __syncthreads();
  if (threadIdx.x == 0)
    partials[blockIdx.x] = (wsum[0] + wsum[1]) + (wsum[2] + wsum[3]);
}

__global__ __launch_bounds__(256) void chamfer_final(
    const float* __restrict__ partials, float* __restrict__ out) {
  float s = partials[threadIdx.x];
  #pragma unroll
  for (int off = 32; off > 0; off >>= 1) s += __shfl_down(s, off, 64);
  __shared__ float wsum[4];
  if ((threadIdx.x & 63) == 0) wsum[threadIdx.x >> 6] = s;
  __syncthreads();
  if (threadIdx.x == 0) out[0] = (wsum[0] + wsum[1]) + (wsum[2] + wsum[3]);
}

extern "C" void kernel_launch(void* const* d_in, const int* in_sizes, int n_in,
                              void* d_out, int out_size, void* d_ws, size_t ws_size,
                              hipStream_t stream) {
  const float* c1 = (const float*)d_in[0];
  const float* c2 = (const float*)d_in[1];
  float* out = (float*)d_out;

  char* ws = (char*)d_ws;
  unsigned* minbuf = (unsigned*)ws;                       // 65536 u32 (rows | cols)
  unsigned* rowbuf = minbuf;
  unsigned* colbuf = minbuf + BATCH * NPTS;
  float* partials = (float*)(ws + (size_t)NSLOTS * 4);    // 256 f32
  unsigned short* arep = (unsigned short*)(ws + (size_t)NSLOTS * 4 + 1024);
  unsigned short* brep = arep + (size_t)BATCH * NPTS * 16;

  init_min<<<NSLOTS / 256, 256, 0, stream>>>(minbuf);
  prep<<<(BATCH * NPTS + 255) / 256, 256, 0, stream>>>(c1, c2, arep, brep);
  chamfer_mfma<<<BATCH * 64 * NJ, 256, 0, stream>>>(arep, brep, rowbuf, colbuf);
  chamfer_loss<<<NSLOTS / 256, 256, 0, stream>>>(minbuf, partials);
  chamfer_final<<<1, 256, 0, stream>>>(partials, out);
}

// Round 4
// 39.212 us; speedup vs baseline: 2.9533x; 2.9533x over previous
//
#include <hip/hip_runtime.h>

// Chamfer via MFMA, direction-split, atomic-free. B=4, N=M=8192, D=3, fp32.
// w(i,j) = q.t - 0.5|q|^2 - 0.5|t|^2 = -d^2/2; NN dist = -2 * max_j w.
// One 32x32x16 bf16 MFMA = 1024 pairs. Each wave owns one 32-query i-tile,
// loops a j-chunk keeping row-max in regs (dual acc -> v_max3), then lane
// butterfly + direct stores. No atomics (round 3: 8.4M col atomics = 80% stall).
// bf16 hi/lo rep (validated round 3, absmax 0):
//   A(q) = [qh(3), ql(3), qh(3), hq_h, hq_l,  1,  1, 0,0,0]
//   B(t) = [th(3), th(3), tl(3),  -1,  -1, -ht_h, -ht_l, 0,0,0]

#define NPTS   8192
#define BATCH  4
#define NJ     2
#define JCHUNK (NPTS / NJ)       // 4096
#define JTILES (JCHUNK / 32)     // 128
#define NSLOTS (2 * BATCH * NPTS)  // 65536

typedef __attribute__((ext_vector_type(8))) short short8v;
typedef __attribute__((ext_vector_type(16))) float f32x16;

__device__ __forceinline__ unsigned short f2bf(float x) {   // RNE bf16
  unsigned u = __float_as_uint(x);
  unsigned r = u + 0x7FFFu + ((u >> 16) & 1u);
  return (unsigned short)(r >> 16);
}
__device__ __forceinline__ float bf2f(unsigned short b) {
  return __uint_as_float((unsigned)b << 16);
}

__global__ __launch_bounds__(256) void prep(
    const float* __restrict__ c1, const float* __restrict__ c2,
    unsigned short* __restrict__ a1, unsigned short* __restrict__ a2,
    unsigned short* __restrict__ b1, unsigned short* __restrict__ b2) {
  int pid = blockIdx.x * 256 + threadIdx.x;
  if (pid >= BATCH * NPTS) return;
  const unsigned short one = 0x3F80u, negone = 0xBF80u;
  const float* cs[2] = {c1, c2};
  unsigned short* as[2] = {a1, a2};
  unsigned short* bs[2] = {b1, b2};
  #pragma unroll
  for (int c = 0; c < 2; ++c) {
    float x = cs[c][pid * 3 + 0], y = cs[c][pid * 3 + 1], z = cs[c][pid * 3 + 2];
    unsigned short xh = f2bf(x), yh = f2bf(y), zh = f2bf(z);
    unsigned short xl = f2bf(x - bf2f(xh)), yl = f2bf(y - bf2f(yh)),
                   zl = f2bf(z - bf2f(zh));
    float hn = 0.5f * (x * x + y * y + z * z);
    unsigned short hh = f2bf(hn), hl = f2bf(hn - bf2f(hh));
    unsigned short va[16] = {xh, yh, zh, xl, yl, zl, xh, yh, zh,
                             hh, hl, one, one, 0, 0, 0};
    unsigned short nh = hh ^ 0x8000u, nl = hl ^ 0x8000u;
    unsigned short vb[16] = {xh, yh, zh, xh, yh, zh, xl, yl, zl,
                             negone, negone, nh, nl, 0, 0, 0};
    uint4* da = (uint4*)(as[c] + (size_t)pid * 16);
    da[0] = *(const uint4*)&va[0];
    da[1] = *(const uint4*)&va[8];
    uint4* db = (uint4*)(bs[c] + (size_t)pid * 16);
    db[0] = *(const uint4*)&vb[0];
    db[1] = *(const uint4*)&vb[8];
  }
}

// grid = 2(dir) x 4(b) x 64(iblk) x NJ(jc) = 1024 blocks x 4 waves.
// Wave owns i-tile iblk*4+wave (32 queries), loops JTILES target tiles.
__global__ __launch_bounds__(256, 4) void chamfer_mfma(
    const unsigned short* __restrict__ a1, const unsigned short* __restrict__ a2,
    const unsigned short* __restrict__ b1, const unsigned short* __restrict__ b2,
    float* __restrict__ rowbuf) {
  int bid  = blockIdx.x;
  int jc   = bid & (NJ - 1);
  int iblk = (bid >> 1) & 63;
  int b    = (bid >> 7) & 3;
  int dir  = bid >> 9;

  const unsigned short* A = dir ? a2 : a1;   // queries
  const unsigned short* B = dir ? b1 : b2;   // targets

  int wave = threadIdx.x >> 6;
  int lane = threadIdx.x & 63;
  int i0 = (iblk * 4 + wave) * 32;
  int j0 = jc * JCHUNK;

  short8v afrag = *(const short8v*)(const void*)(
      A + ((size_t)b * NPTS + i0 + (lane & 31)) * 16 + (lane >> 5) * 8);
  const unsigned short* Bp =
      B + ((size_t)b * NPTS + j0 + (lane & 31)) * 16 + (lane >> 5) * 8;

  f32x16 zero;
  #pragma unroll
  for (int i = 0; i < 16; ++i) zero[i] = 0.0f;
  f32x16 mrow;
  #pragma unroll
  for (int i = 0; i < 16; ++i) mrow[i] = -3.4e38f;

  for (int jt = 0; jt < JTILES; jt += 2) {
    short8v bf0 = *(const short8v*)(const void*)(Bp + (size_t)jt * 32 * 16);
    short8v bf1 = *(const short8v*)(const void*)(Bp + (size_t)(jt + 1) * 32 * 16);
    f32x16 acc0 = __builtin_amdgcn_mfma_f32_32x32x16_bf16(afrag, bf0, zero, 0, 0, 0);
    f32x16 acc1 = __builtin_amdgcn_mfma_f32_32x32x16_bf16(afrag, bf1, zero, 0, 0, 0);
    #pragma unroll
    for (int r = 0; r < 16; ++r)
      mrow[r] = fmaxf(fmaxf(acc0[r], acc1[r]), mrow[r]);   // v_max3_f32
  }

  // reduce over the 32 columns held across lanes of each half
  #pragma unroll
  for (int r = 0; r < 16; ++r) {
    float v = mrow[r];
    v = fmaxf(v, __shfl_xor(v, 1, 64));
    v = fmaxf(v, __shfl_xor(v, 2, 64));
    v = fmaxf(v, __shfl_xor(v, 4, 64));
    v = fmaxf(v, __shfl_xor(v, 8, 64));
    v = fmaxf(v, __shfl_xor(v, 16, 64));
    mrow[r] = v;
  }
  if ((lane & 31) == 0) {
    int half = lane >> 5;
    float* rb = rowbuf + (size_t)jc * NSLOTS + ((size_t)dir * BATCH + b) * NPTS + i0;
    #pragma unroll
    for (int r = 0; r < 16; ++r) {
      int row = (r & 3) + 8 * (r >> 2) + 4 * half;   // verified 32x32 C/D map
      rb[row] = mrow[r];
    }
  }
}

__global__ __launch_bounds__(256) void chamfer_loss(
    const float* __restrict__ rowbuf, float* __restrict__ partials) {
  int slot = blockIdx.x * 256 + threadIdx.x;
  float w = fmaxf(rowbuf[slot], rowbuf[NSLOTS + slot]);
  float s = -2.0f * w;   // min squared distance for this point
  #pragma unroll
  for (int off = 32; off > 0; off >>= 1) s += __shfl_down(s, off, 64);
  __shared__ float wsum[4];
  if ((threadIdx.x & 63) == 0) wsum[threadIdx.x >> 6] = s;
  __syncthreads();
  if (threadIdx.x == 0)
    partials[blockIdx.x] = (wsum[0] + wsum[1]) + (wsum[2] + wsum[3]);
}

__global__ __launch_bounds__(256) void chamfer_final(
    const float* __restrict__ partials, float* __restrict__ out) {
  float s = partials[threadIdx.x];
  #pragma unroll
  for (int off = 32; off > 0; off >>= 1) s += __shfl_down(s, off, 64);
  __shared__ float wsum[4];
  if ((threadIdx.x & 63) == 0) wsum[threadIdx.x >> 6] = s;
  __syncthreads();
  if (threadIdx.x == 0) out[0] = (wsum[0] + wsum[1]) + (wsum[2] + wsum[3]);
}

extern "C" void kernel_launch(void* const* d_in, const int* in_sizes, int n_in,
                              void* d_out, int out_size, void* d_ws, size_t ws_size,
                              hipStream_t stream) {
  const float* c1 = (const float*)d_in[0];
  const float* c2 = (const float*)d_in[1];
  float* out = (float*)d_out;

  char* ws = (char*)d_ws;
  float* rowbuf = (float*)ws;                                    // NJ*65536 f32
  float* partials = (float*)(ws + (size_t)NJ * NSLOTS * 4);      // 256 f32
  unsigned short* a1 = (unsigned short*)(ws + (size_t)NJ * NSLOTS * 4 + 1024);
  unsigned short* a2 = a1 + (size_t)BATCH * NPTS * 16;
  unsigned short* b1 = a2 + (size_t)BATCH * NPTS * 16;
  unsigned short* b2 = b1 + (size_t)BATCH * NPTS * 16;

  prep<<<(BATCH * NPTS + 255) / 256, 256, 0, stream>>>(c1, c2, a1, a2, b1, b2);
  chamfer_mfma<<<2 * BATCH * 64 * NJ, 256, 0, stream>>>(a1, a2, b1, b2, rowbuf);
  chamfer_loss<<<NSLOTS / 256, 256, 0, stream>>>(rowbuf, partials);
  chamfer_final<<<1, 256, 0, stream>>>(partials, out);
}

// Round 5
// 36.949 us; speedup vs baseline: 3.1342x; 1.0613x over previous
//
#include <hip/hip_runtime.h>

// Chamfer via MFMA, 3-kernel pipeline. B=4, N=M=8192, D=3, fp32.
// w(i,j) = q.t - 0.5|q|^2 - 0.5|t|^2 = -d^2/2; NN dist^2 = -2 * max_j w.
// One 32x32x16 bf16 MFMA = 1024 pairs; per-wave row-max in regs with v_max3
// (8 per tile = VALU floor), depth-2 register prefetch of B fragments
// (round 4: no prefetch -> load-latency-bound at ~25-30us).
// NJ=2 j-chunks merged via atomicMax on order-encoded u32 (2 contenders,
// integer max => deterministic). prep zero-inits rowbuf; loss_final is one
// 1024-thread block -> out[0].
// bf16 hi/lo rep (validated rounds 3-4, absmax 0):
//   A(q) = [qh(3), ql(3), qh(3), hq_h, hq_l,  1,  1, 0,0,0]
//   B(t) = [th(3), th(3), tl(3),  -1,  -1, -ht_h, -ht_l, 0,0,0]

#define NPTS   8192
#define BATCH  4
#define NJ     2
#define JCHUNK (NPTS / NJ)         // 4096
#define JTILES (JCHUNK / 32)       // 128
#define NSLOTS (2 * BATCH * NPTS)  // 65536

typedef __attribute__((ext_vector_type(8))) short short8v;
typedef __attribute__((ext_vector_type(16))) float f32x16;

__device__ __forceinline__ unsigned enc_f32(float f) {
  unsigned u = __float_as_uint(f);
  return (u & 0x80000000u) ? ~u : (u | 0x80000000u);
}
__device__ __forceinline__ float dec_f32(unsigned u) {
  u = (u & 0x80000000u) ? (u ^ 0x80000000u) : ~u;
  return __uint_as_float(u);
}
__device__ __forceinline__ unsigned short f2bf(float x) {   // RNE bf16
  unsigned u = __float_as_uint(x);
  unsigned r = u + 0x7FFFu + ((u >> 16) & 1u);
  return (unsigned short)(r >> 16);
}
__device__ __forceinline__ float bf2f(unsigned short b) {
  return __uint_as_float((unsigned)b << 16);
}

__global__ __launch_bounds__(256) void prep(
    const float* __restrict__ c1, const float* __restrict__ c2,
    unsigned short* __restrict__ a1, unsigned short* __restrict__ a2,
    unsigned short* __restrict__ b1, unsigned short* __restrict__ b2,
    unsigned* __restrict__ rowbuf) {
  int pid = blockIdx.x * 256 + threadIdx.x;
  if (pid >= BATCH * NPTS) return;
  rowbuf[pid] = 0u;                    // below enc of any real float
  rowbuf[pid + BATCH * NPTS] = 0u;
  const unsigned short one = 0x3F80u, negone = 0xBF80u;
  const float* cs[2] = {c1, c2};
  unsigned short* as[2] = {a1, a2};
  unsigned short* bs[2] = {b1, b2};
  #pragma unroll
  for (int c = 0; c < 2; ++c) {
    float x = cs[c][pid * 3 + 0], y = cs[c][pid * 3 + 1], z = cs[c][pid * 3 + 2];
    unsigned short xh = f2bf(x), yh = f2bf(y), zh = f2bf(z);
    unsigned short xl = f2bf(x - bf2f(xh)), yl = f2bf(y - bf2f(yh)),
                   zl = f2bf(z - bf2f(zh));
    float hn = 0.5f * (x * x + y * y + z * z);
    unsigned short hh = f2bf(hn), hl = f2bf(hn - bf2f(hh));
    unsigned short va[16] = {xh, yh, zh, xl, yl, zl, xh, yh, zh,
                             hh, hl, one, one, 0, 0, 0};
    unsigned short nh = hh ^ 0x8000u, nl = hl ^ 0x8000u;
    unsigned short vb[16] = {xh, yh, zh, xh, yh, zh, xl, yl, zl,
                             negone, negone, nh, nl, 0, 0, 0};
    uint4* da = (uint4*)(as[c] + (size_t)pid * 16);
    da[0] = *(const uint4*)&va[0];
    da[1] = *(const uint4*)&va[8];
    uint4* db = (uint4*)(bs[c] + (size_t)pid * 16);
    db[0] = *(const uint4*)&vb[0];
    db[1] = *(const uint4*)&vb[8];
  }
}

// grid = 2(dir) x 4(b) x 64(iblk) x NJ(jc) = 1024 blocks x 4 waves.
// Wave owns i-tile iblk*4+wave (32 queries), loops JTILES=128 target tiles
// with depth-2 register prefetch (4 fragments in flight).
__global__ __launch_bounds__(256, 4) void chamfer_mfma(
    const unsigned short* __restrict__ a1, const unsigned short* __restrict__ a2,
    const unsigned short* __restrict__ b1, const unsigned short* __restrict__ b2,
    unsigned* __restrict__ rowbuf) {
  int bid  = blockIdx.x;
  int jc   = bid & (NJ - 1);
  int iblk = (bid >> 1) & 63;
  int b    = (bid >> 7) & 3;
  int dir  = bid >> 9;

  const unsigned short* A = dir ? a2 : a1;   // queries
  const unsigned short* B = dir ? b1 : b2;   // targets

  int wave = threadIdx.x >> 6;
  int lane = threadIdx.x & 63;
  int i0 = (iblk * 4 + wave) * 32;
  int j0 = jc * JCHUNK;

  short8v afrag = *(const short8v*)(const void*)(
      A + ((size_t)b * NPTS + i0 + (lane & 31)) * 16 + (lane >> 5) * 8);
  const short8v* Bp = (const short8v*)(const void*)(
      B + ((size_t)b * NPTS + j0 + (lane & 31)) * 16 + (lane >> 5) * 8);
  // one 32-point tile = 512 shorts = 64 short8v

  f32x16 zero;
  #pragma unroll
  for (int i = 0; i < 16; ++i) zero[i] = 0.0f;
  f32x16 mrow;
  #pragma unroll
  for (int i = 0; i < 16; ++i) mrow[i] = -3.4e38f;

#define LD(jt) Bp[(size_t)(jt) * 64]
#define MAXPAIR(x, y)                                                          \
  do {                                                                         \
    f32x16 accA = __builtin_amdgcn_mfma_f32_32x32x16_bf16(afrag, (x), zero, 0, 0, 0); \
    f32x16 accB = __builtin_amdgcn_mfma_f32_32x32x16_bf16(afrag, (y), zero, 0, 0, 0); \
    _Pragma("unroll") for (int r = 0; r < 16; ++r)                             \
        mrow[r] = fmaxf(fmaxf(accA[r], accB[r]), mrow[r]); /* v_max3 */        \
  } while (0)

  short8v c0 = LD(0), c1 = LD(1), c2 = LD(2), c3 = LD(3);
  int jt = 0;
  for (; jt + 4 < JTILES; jt += 4) {
    short8v n0 = LD(jt + 4), n1 = LD(jt + 5);
    MAXPAIR(c0, c1);
    short8v n2 = LD(jt + 6), n3 = LD(jt + 7);
    MAXPAIR(c2, c3);
    c0 = n0; c1 = n1; c2 = n2; c3 = n3;
  }
  MAXPAIR(c0, c1);
  MAXPAIR(c2, c3);
#undef LD
#undef MAXPAIR

  // reduce over the 32 columns held across lanes of each half
  #pragma unroll
  for (int r = 0; r < 16; ++r) {
    float v = mrow[r];
    v = fmaxf(v, __shfl_xor(v, 1, 64));
    v = fmaxf(v, __shfl_xor(v, 2, 64));
    v = fmaxf(v, __shfl_xor(v, 4, 64));
    v = fmaxf(v, __shfl_xor(v, 8, 64));
    v = fmaxf(v, __shfl_xor(v, 16, 64));
    mrow[r] = v;
  }
  if ((lane & 31) == 0) {
    int half = lane >> 5;
    unsigned* rb = rowbuf + ((size_t)dir * BATCH + b) * NPTS + i0;
    #pragma unroll
    for (int r = 0; r < 16; ++r) {
      int row = (r & 3) + 8 * (r >> 2) + 4 * half;   // verified 32x32 C/D map
      atomicMax(rb + row, enc_f32(mrow[r]));         // 2 contenders (NJ=2)
    }
  }
}

__global__ __launch_bounds__(1024) void loss_final(
    const unsigned* __restrict__ rowbuf, float* __restrict__ out) {
  int tid = threadIdx.x;
  float s = 0.0f;
  #pragma unroll
  for (int k = 0; k < NSLOTS / 1024; ++k) {
    float w = dec_f32(rowbuf[k * 1024 + tid]);
    s = fmaf(-2.0f, w, s);   // min squared distance for this slot
  }
  #pragma unroll
  for (int off = 32; off > 0; off >>= 1) s += __shfl_down(s, off, 64);
  __shared__ float wsum[16];
  if ((tid & 63) == 0) wsum[tid >> 6] = s;
  __syncthreads();
  if (tid == 0) {
    float t = 0.0f;
    #pragma unroll
    for (int w2 = 0; w2 < 16; ++w2) t += wsum[w2];
    out[0] = t;
  }
}

extern "C" void kernel_launch(void* const* d_in, const int* in_sizes, int n_in,
                              void* d_out, int out_size, void* d_ws, size_t ws_size,
                              hipStream_t stream) {
  const float* c1 = (const float*)d_in[0];
  const float* c2 = (const float*)d_in[1];
  float* out = (float*)d_out;

  char* ws = (char*)d_ws;
  unsigned* rowbuf = (unsigned*)ws;                          // 65536 u32 = 256 KB
  unsigned short* a1 = (unsigned short*)(ws + (size_t)NSLOTS * 4);
  unsigned short* a2 = a1 + (size_t)BATCH * NPTS * 16;       // 1 MB each
  unsigned short* b1 = a2 + (size_t)BATCH * NPTS * 16;
  unsigned short* b2 = b1 + (size_t)BATCH * NPTS * 16;

  prep<<<(BATCH * NPTS) / 256, 256, 0, stream>>>(c1, c2, a1, a2, b1, b2, rowbuf);
  chamfer_mfma<<<2 * BATCH * 64 * NJ, 256, 0, stream>>>(a1, a2, b1, b2, rowbuf);
  loss_final<<<1, 1024, 0, stream>>>(rowbuf, out);
}